// Round 14
// baseline (1085.579 us; speedup 1.0000x reference)
//
#include <hip/hip_runtime.h>
#include <stdint.h>

#define B_DIM 4096
#define DIN   4096
#define E_DIM 2048
#define H_DIM 2048
#define V_DIM 32000

typedef __attribute__((ext_vector_type(8))) short s8v;     // 8 x bf16 (MFMA A/B frag)
typedef __attribute__((ext_vector_type(4))) float f4v;     // MFMA C/D frag
typedef __attribute__((ext_vector_type(4))) int   i4v;
typedef __attribute__((ext_vector_type(8))) int   i8v;     // fp8 MFMA A/B operand (32 B)
typedef __attribute__((ext_vector_type(4))) uint  u4v;     // native 16B int vector (nt ld/st)
typedef __attribute__((ext_vector_type(4))) float f4n;     // native 16B float vector (nt ld/st)

__device__ __forceinline__ ushort f2bf(float f) {
    union { float f; uint32_t u; } v; v.f = f;
    uint32_t u = v.u;
    return (ushort)((u + 0x7FFFu + ((u >> 16) & 1u)) >> 16);
}
__device__ __forceinline__ float bf2f(ushort h) {
    union { uint32_t u; float f; } v; v.u = ((uint32_t)h) << 16;
    return v.f;
}

// float -> OCP e4m3fn, RNE (values expected pre-scaled into normal range)
__device__ __forceinline__ uint8_t f2fp8(float x) {
    union { float f; uint32_t u; } v; v.f = x;
    uint8_t sign = (uint8_t)((v.u >> 24) & 0x80u);
    uint32_t a = v.u & 0x7FFFFFFFu;
    if (a >= 0x43E00000u) return sign | 0x7E;            // >= 448 -> clamp
    uint32_t r = a + 0x0007FFFFu + ((a >> 20) & 1u);     // RNE at bit 20
    int e = (int)(r >> 23) - 127 + 7;
    if (e <= 0) {                                         // subnormal: multiples of 2^-9
        float s = fabsf(x);
        int q = (int)(s * 512.0f + 0.5f);
        if (q > 7) q = 7;
        return sign | (uint8_t)q;
    }
    uint32_t m = (r >> 20) & 7u;
    uint8_t b = (uint8_t)((e << 3) | m);
    if (b == 0x7F) b = 0x7E;                              // avoid NaN encoding
    return sign | b;
}

// ---------------- fp32 -> bf16 plain convert ----------------
__global__ void k_cvt(const float* __restrict__ src, ushort* __restrict__ dst, int n4) {
    int i = blockIdx.x * blockDim.x + threadIdx.x;
    if (i >= n4) return;
    float4 v = *(const float4*)(src + (size_t)i * 4);
    ushort4 o;
    o.x = f2bf(v.x); o.y = f2bf(v.y); o.z = f2bf(v.z); o.w = f2bf(v.w);
    *(ushort4*)(dst + (size_t)i * 4) = o;
}

// hidden [4096][2048] fp32 -> A2 (fp8 x32) right half (row stride 4096, col offset 2048)
__global__ void k_cvt_hidden(const float* __restrict__ src, uint8_t* __restrict__ dst) {
    int i = blockIdx.x * blockDim.x + threadIdx.x;
    int b = i >> 9;
    int c = (i & 511) << 2;
    float4 v = *(const float4*)(src + (size_t)b * H_DIM + c);
    uchar4 o;
    o.x = f2fp8(v.x * 32.0f); o.y = f2fp8(v.y * 32.0f);
    o.z = f2fp8(v.z * 32.0f); o.w = f2fp8(v.w * 32.0f);
    *(uchar4*)(dst + (size_t)b * 4096 + 2048 + c) = o;
}

// ---------------- transpose + convert: src fp32 [K x N] -> dst bf16 [N x K] ----------------
__global__ void k_transpose_bf16(const float* __restrict__ src, ushort* __restrict__ dst,
                                 int srcCols, int dstStride, int dstRowOff, int dstColOff) {
    __shared__ float tile[32][33];
    int tx = threadIdx.x, ty = threadIdx.y;
    int n0 = blockIdx.x * 32, k0 = blockIdx.y * 32;
#pragma unroll
    for (int i = 0; i < 4; i++)
        tile[ty + 8 * i][tx] = src[(size_t)(k0 + ty + 8 * i) * srcCols + n0 + tx];
    __syncthreads();
#pragma unroll
    for (int i = 0; i < 4; i++) {
        int n = ty + 8 * i;
        dst[(size_t)(dstRowOff + n0 + n) * dstStride + dstColOff + k0 + tx] = f2bf(tile[tx][n]);
    }
}

// transpose + convert + scale: src fp32 [K x N] -> dst fp8 [N x K], val*32 (scale 2^-5 in MFMA)
__global__ void k_transpose_fp8(const float* __restrict__ src, uint8_t* __restrict__ dst,
                                int srcCols, int dstStride) {
    __shared__ float tile[32][33];
    int tx = threadIdx.x, ty = threadIdx.y;
    int n0 = blockIdx.x * 32, k0 = blockIdx.y * 32;
#pragma unroll
    for (int i = 0; i < 4; i++)
        tile[ty + 8 * i][tx] = src[(size_t)(k0 + ty + 8 * i) * srcCols + n0 + tx];
    __syncthreads();
#pragma unroll
    for (int i = 0; i < 4; i++) {
        int n = ty + 8 * i;
        dst[(size_t)(n0 + n) * dstStride + k0 + tx] = f2fp8(tile[tx][n] * 32.0f);
    }
}

// all 8 gate-interleaved transposes in one launch -> fp8 (x32), WUT8 [8192][4096]
// 128-col-tile packing: col(g,h) = (h>>5)*128 + ((h>>4)&1)*64 + g*16 + (h&15)
__global__ void k_transpose_gate8(const float* __restrict__ W0, const float* __restrict__ W1,
                                  const float* __restrict__ W2, const float* __restrict__ W3,
                                  const float* __restrict__ U0, const float* __restrict__ U1,
                                  const float* __restrict__ U2, const float* __restrict__ U3,
                                  uint8_t* __restrict__ dst) {
    const float* srcs[8] = {W0, W1, W2, W3, U0, U1, U2, U3};
    int z = blockIdx.z;
    const float* src = srcs[z];
    int g = z & 3;
    int dstColOff = (z >> 2) << 11;   // 0 (W) or 2048 (U)
    __shared__ float tile[32][33];
    int tx = threadIdx.x, ty = threadIdx.y;
    int n0 = blockIdx.x * 32, k0 = blockIdx.y * 32;
#pragma unroll
    for (int i = 0; i < 4; i++)
        tile[ty + 8 * i][tx] = src[(size_t)(k0 + ty + 8 * i) * H_DIM + n0 + tx];
    __syncthreads();
#pragma unroll
    for (int i = 0; i < 4; i++) {
        int h = n0 + ty + 8 * i;
        int drow = ((h >> 5) << 7) + (((h >> 4) & 1) << 6) + (g << 4) + (h & 15);
        dst[(size_t)drow * 4096 + dstColOff + k0 + tx] = f2fp8(tile[tx][ty + 8 * i] * 32.0f);
    }
}

__global__ void k_biaspack(const float* __restrict__ b0, const float* __restrict__ bh0,
                           const float* __restrict__ b1, const float* __restrict__ bh1,
                           const float* __restrict__ b2, const float* __restrict__ bh2,
                           const float* __restrict__ b3, const float* __restrict__ bh3,
                           float* __restrict__ out) {
    int h = blockIdx.x * blockDim.x + threadIdx.x;
    if (h >= H_DIM) return;
    int base = ((h >> 5) << 7) + (((h >> 4) & 1) << 6) + (h & 15);
    out[base]      = b0[h] + bh0[h];   // g=0: f
    out[base + 16] = b1[h] + bh1[h];   // g=1: i
    out[base + 32] = b2[h] + bh2[h];   // g=2: c
    out[base + 48] = b3[h] + bh3[h];   // g=3: o
}

// ---------------- 128x128 2-phase bf16 GEMM (emb only), XCD-pinned ----------------
__global__ __launch_bounds__(256, 4)
void k_gemm_bt(const ushort* __restrict__ A, const ushort* __restrict__ Bt,
               uint8_t* __restrict__ Cf8, const float* __restrict__ bias,
               int N, int K, int lda, int ldb, int ldc) {
    __shared__ __align__(16) ushort ldsA[128 * 64];
    __shared__ __align__(16) ushort ldsB[128 * 64];
    const int t = threadIdx.x;
    const int wid = t >> 6, lane = t & 63;

    int bid = blockIdx.x;
    int mt  = ((bid & 7) << 2) | ((bid >> 3) & 3);
    int nt  = bid >> 5;
    int m0  = mt << 7, n0 = nt << 7;

    f4v acc[4][4];
#pragma unroll
    for (int i = 0; i < 4; i++)
#pragma unroll
        for (int j = 0; j < 4; j++) acc[i][j] = (f4v){0.f, 0.f, 0.f, 0.f};

    const int wr = wid >> 1, wc = wid & 1;

    const int kTiles = K >> 6;
    for (int kt = 0; kt < kTiles; ++kt) {
#pragma unroll
        for (int c = 0; c < 4; ++c) {
            int idx = c * 256 + wid * 64 + lane;
            int row = idx >> 3;
            int kb  = (idx & 7) << 4;
            const ushort* gA = A  + (size_t)(m0 + row) * lda + (kt << 6) + (kb >> 1);
            const ushort* gB = Bt + (size_t)(n0 + row) * ldb + (kt << 6) + (kb >> 1);
            char* lA = (char*)ldsA + (size_t)(c * 256 + wid * 64) * 16;
            char* lB = (char*)ldsB + (size_t)(c * 256 + wid * 64) * 16;
            __builtin_amdgcn_global_load_lds((const __attribute__((address_space(1))) void*)gA,
                                             (__attribute__((address_space(3))) void*)lA, 16, 0, 0);
            __builtin_amdgcn_global_load_lds((const __attribute__((address_space(1))) void*)gB,
                                             (__attribute__((address_space(3))) void*)lB, 16, 0, 0);
        }
        __syncthreads();

#pragma unroll
        for (int ks = 0; ks < 2; ++ks) {
            s8v af[4], bfr[4];
#pragma unroll
            for (int m = 0; m < 4; ++m) {
                int r = wr * 64 + m * 16 + (lane & 15);
                int kb = ks * 64 + ((lane >> 4) << 4);
                af[m] = *(const s8v*)((const char*)ldsA + r * 128 + kb);
            }
#pragma unroll
            for (int n = 0; n < 4; ++n) {
                int r = wc * 64 + n * 16 + (lane & 15);
                int kb = ks * 64 + ((lane >> 4) << 4);
                bfr[n] = *(const s8v*)((const char*)ldsB + r * 128 + kb);
            }
#pragma unroll
            for (int m = 0; m < 4; ++m)
#pragma unroll
                for (int n = 0; n < 4; ++n)
                    acc[m][n] = __builtin_amdgcn_mfma_f32_16x16x32_bf16(af[m], bfr[n], acc[m][n], 0, 0, 0);
        }
        __syncthreads();
    }

#pragma unroll
    for (int n = 0; n < 4; ++n) {
        int cg = n0 + wc * 64 + n * 16 + (lane & 15);
        float bv = bias[cg];
#pragma unroll
        for (int m = 0; m < 4; ++m) {
            int rbase = m0 + wr * 64 + m * 16 + ((lane >> 4) << 2);
#pragma unroll
            for (int r = 0; r < 4; ++r)
                Cf8[(size_t)(rbase + r) * ldc + cg] = f2fp8((acc[m][n][r] + bv) * 32.0f);
        }
    }
}

// ---------------- gate GEMM: MX-fp8 16x16x128, 128x128 tile, BK=128, XCD-pinned ----------------
__global__ __launch_bounds__(256, 4)
void k_gatemx(const uint8_t* __restrict__ A, const uint8_t* __restrict__ Bt,
              const float* __restrict__ bias, const float* __restrict__ cell,
              float* __restrict__ outH, float* __restrict__ outC,
              uint8_t* __restrict__ hidF8) {
    __shared__ __align__(16) uint8_t ldsAB[2][128 * 128];   // 32 KB
    const int t = threadIdx.x;
    const int wid = t >> 6, lane = t & 63;
    const int wrr = wid >> 1, wcc = wid & 1;

    int bid = blockIdx.x;
    int mt  = ((bid & 7) << 2) | ((bid >> 3) & 3);
    int nt  = bid >> 5;                  // 0..63
    int m0  = mt << 7, n0 = nt << 7;
    const int K = 4096;

    int offA[4], offB[4];
#pragma unroll
    for (int c = 0; c < 4; ++c) {
        int idx = c * 256 + t;
        int row = idx >> 3;
        int cb  = ((idx & 7) ^ (row & 7)) << 4;
        offA[c] = (m0 + row) * K + cb;
        offB[c] = (n0 + row) * K + cb;
    }

    f4v acc[4][4];
#pragma unroll
    for (int i = 0; i < 4; ++i)
#pragma unroll
        for (int j = 0; j < 4; ++j) acc[i][j] = (f4v){0.f, 0.f, 0.f, 0.f};

    const int l15 = lane & 15;
    const int sw  = (lane & 7) << 4;
    const int o0  = ((lane >> 4) << 5) ^ sw;
    const int o1  = o0 ^ 16;

    const int kTiles = K >> 7;           // 32
    for (int kt = 0; kt < kTiles; ++kt) {
#pragma unroll
        for (int c = 0; c < 4; ++c) {
            __builtin_amdgcn_global_load_lds(
                (const __attribute__((address_space(1))) void*)(A + offA[c] + (kt << 7)),
                (__attribute__((address_space(3))) void*)&ldsAB[0][(c * 256 + wid * 64) * 16], 16, 0, 0);
            __builtin_amdgcn_global_load_lds(
                (const __attribute__((address_space(1))) void*)(Bt + offB[c] + (kt << 7)),
                (__attribute__((address_space(3))) void*)&ldsAB[1][(c * 256 + wid * 64) * 16], 16, 0, 0);
        }
        __syncthreads();

        i8v af[4], bf[4];
#pragma unroll
        for (int m = 0; m < 4; ++m) {
            int row = wrr * 64 + m * 16 + l15;
            i4v lo = *(const i4v*)&ldsAB[0][row * 128 + o0];
            i4v hi = *(const i4v*)&ldsAB[0][row * 128 + o1];
            af[m] = __builtin_shufflevector(lo, hi, 0, 1, 2, 3, 4, 5, 6, 7);
        }
#pragma unroll
        for (int n = 0; n < 4; ++n) {
            int row = wcc * 64 + n * 16 + l15;
            i4v lo = *(const i4v*)&ldsAB[1][row * 128 + o0];
            i4v hi = *(const i4v*)&ldsAB[1][row * 128 + o1];
            bf[n] = __builtin_shufflevector(lo, hi, 0, 1, 2, 3, 4, 5, 6, 7);
        }
#pragma unroll
        for (int m = 0; m < 4; ++m)
#pragma unroll
            for (int n = 0; n < 4; ++n)
                acc[m][n] = __builtin_amdgcn_mfma_scale_f32_16x16x128_f8f6f4(
                    af[m], bf[n], acc[m][n], 0, 0, 0, 122, 0, 122);
        __syncthreads();
    }

    // ---- fused LSTM epilogue: lane's 4 n-frags = gates f,i,c,o of one h ----
    int h = (n0 >> 2) + wcc * 16 + l15;
    float bv[4];
#pragma unroll
    for (int n = 0; n < 4; ++n) bv[n] = bias[n0 + wcc * 64 + n * 16 + l15];
#pragma unroll
    for (int m = 0; m < 4; ++m) {
#pragma unroll
        for (int r = 0; r < 4; ++r) {
            int b = m0 + wrr * 64 + m * 16 + ((lane >> 4) << 2) + r;
            float pf_ = acc[m][0][r] + bv[0];
            float pi_ = acc[m][1][r] + bv[1];
            float pc_ = acc[m][2][r] + bv[2];
            float po_ = acc[m][3][r] + bv[3];
            float fg = 1.f / (1.f + __expf(-pf_));
            float ig = 1.f / (1.f + __expf(-pi_));
            float gg = tanhf(pc_);
            float og = 1.f / (1.f + __expf(-po_));
            size_t off = (size_t)b * H_DIM + h;
            float nc = fg * cell[off] + ig * gg;
            float nh = og * tanhf(nc);
            outC[off] = nc;
            outH[off] = nh;
            hidF8[off] = f2fp8(nh * 8.0f);   // head A pre-scale 2^3 (scale 124)
        }
    }
}

// ---------------- head GEMM: MX-fp8 16x16x128, 128x128 tile, BK=128, XCD-pinned ----------------
__global__ __launch_bounds__(256, 4)
void k_gemm_mx(const uint8_t* __restrict__ A, const uint8_t* __restrict__ Bt,
               ushort* __restrict__ Lbf, const float* __restrict__ bias,
               float2* __restrict__ partials, int N, int K, int ldc, int ncb) {
    __shared__ __align__(16) uint8_t ldsAB[2][128 * 128];
    __shared__ float2 smStat[256];
    const int t = threadIdx.x;
    const int wid = t >> 6, lane = t & 63;
    const int wrr = wid >> 1, wcc = wid & 1;

    int bid = blockIdx.x;
    int mt  = ((bid & 7) << 2) | ((bid >> 3) & 3);
    int nt  = bid >> 5;                                  // 0..249
    int m0  = mt << 7, n0 = nt << 7;

    int offA[4], offB[4];
#pragma unroll
    for (int c = 0; c < 4; ++c) {
        int idx = c * 256 + t;
        int row = idx >> 3;
        int cb  = ((idx & 7) ^ (row & 7)) << 4;
        offA[c] = (m0 + row) * K + cb;
        offB[c] = (n0 + row) * K + cb;
    }

    f4v acc[4][4];
#pragma unroll
    for (int i = 0; i < 4; ++i)
#pragma unroll
        for (int j = 0; j < 4; ++j) acc[i][j] = (f4v){0.f, 0.f, 0.f, 0.f};

    const int l15 = lane & 15;
    const int sw  = (lane & 7) << 4;
    const int o0  = ((lane >> 4) << 5) ^ sw;
    const int o1  = o0 ^ 16;

    const int kTiles = K >> 7;
    for (int kt = 0; kt < kTiles; ++kt) {
#pragma unroll
        for (int c = 0; c < 4; ++c) {
            __builtin_amdgcn_global_load_lds(
                (const __attribute__((address_space(1))) void*)(A + offA[c] + (kt << 7)),
                (__attribute__((address_space(3))) void*)&ldsAB[0][(c * 256 + wid * 64) * 16], 16, 0, 0);
            __builtin_amdgcn_global_load_lds(
                (const __attribute__((address_space(1))) void*)(Bt + offB[c] + (kt << 7)),
                (__attribute__((address_space(3))) void*)&ldsAB[1][(c * 256 + wid * 64) * 16], 16, 0, 0);
        }
        __syncthreads();

        i8v af[4], bf[4];
#pragma unroll
        for (int m = 0; m < 4; ++m) {
            int row = wrr * 64 + m * 16 + l15;
            i4v lo = *(const i4v*)&ldsAB[0][row * 128 + o0];
            i4v hi = *(const i4v*)&ldsAB[0][row * 128 + o1];
            af[m] = __builtin_shufflevector(lo, hi, 0, 1, 2, 3, 4, 5, 6, 7);
        }
#pragma unroll
        for (int n = 0; n < 4; ++n) {
            int row = wcc * 64 + n * 16 + l15;
            i4v lo = *(const i4v*)&ldsAB[1][row * 128 + o0];
            i4v hi = *(const i4v*)&ldsAB[1][row * 128 + o1];
            bf[n] = __builtin_shufflevector(lo, hi, 0, 1, 2, 3, 4, 5, 6, 7);
        }
#pragma unroll
        for (int m = 0; m < 4; ++m)
#pragma unroll
            for (int n = 0; n < 4; ++n)
                acc[m][n] = __builtin_amdgcn_mfma_scale_f32_16x16x128_f8f6f4(
                    af[m], bf[n], acc[m][n], 0, 0, 0, 124, 0, 122);
        __syncthreads();
    }

    float bv[4];
#pragma unroll
    for (int n = 0; n < 4; ++n) bv[n] = bias[n0 + wcc * 64 + n * 16 + l15];
    ushort* ctile = (ushort*)&ldsAB[0][0];
#pragma unroll
    for (int m = 0; m < 4; ++m) {
#pragma unroll
        for (int r = 0; r < 4; ++r) {
            int rl = wrr * 64 + m * 16 + ((lane >> 4) << 2) + r;
            float v[4];
#pragma unroll
            for (int n = 0; n < 4; ++n) {
                v[n] = acc[m][n][r] + bv[n];
                ctile[rl * 128 + wcc * 64 + n * 16 + l15] = f2bf(v[n]);
            }
            float mx = fmaxf(fmaxf(v[0], v[1]), fmaxf(v[2], v[3]));
            float ss = __expf(v[0] - mx) + __expf(v[1] - mx) +
                       __expf(v[2] - mx) + __expf(v[3] - mx);
#pragma unroll
            for (int off = 1; off < 16; off <<= 1) {
                float mo = __shfl_xor(mx, off);
                float so = __shfl_xor(ss, off);
                float nm = fmaxf(mx, mo);
                ss = ss * __expf(mx - nm) + so * __expf(mo - nm);
                mx = nm;
            }
            if (l15 == 0) smStat[wcc * 128 + rl] = make_float2(mx, ss);
        }
    }
    __syncthreads();
    if (t < 128) {
        float2 a = smStat[t], b = smStat[128 + t];
        float M = fmaxf(a.x, b.x);
        float S = a.y * __expf(a.x - M) + b.y * __expf(b.x - M);
        partials[(size_t)(m0 + t) * ncb + nt] = make_float2(M, S);
    }
#pragma unroll
    for (int i = 0; i < 8; ++i) {
        int idx = i * 256 + t;
        int row = idx >> 4;
        int c16 = idx & 15;
        u4v val = *(const u4v*)&ctile[row * 128 + c16 * 8];
        __builtin_nontemporal_store(val, (u4v*)&Lbf[(size_t)(m0 + row) * ldc + n0 + c16 * 8]);
    }
}

// ---------------- reduce per-block (m,s) partials -> lse[row] ----------------
__global__ void k_lsefin(const float2* __restrict__ part, float* __restrict__ lse, int ncb) {
    int row = blockIdx.x;
    int l = threadIdx.x;   // 64
    float M = -1e30f, S = 0.f;
    for (int i = l; i < ncb; i += 64) {
        float2 p = part[(size_t)row * ncb + i];
        float nm = fmaxf(M, p.x);
        S = S * __expf(M - nm) + p.y * __expf(p.x - nm);
        M = nm;
    }
#pragma unroll
    for (int off = 1; off < 64; off <<= 1) {
        float Mo = __shfl_xor(M, off);
        float So = __shfl_xor(S, off);
        float nm = fmaxf(M, Mo);
        S = S * __expf(M - nm) + So * __expf(Mo - nm);
        M = nm;
    }
    if (l == 0) lse[row] = M + logf(S);
}

// ---------------- normalize: out = bf16logit - lse[row], nontemporal ----------------
__global__ void k_norm(const ushort* __restrict__ Lbf, const float* __restrict__ lse,
                       float* __restrict__ out) {
    int b = blockIdx.y;
    int c8 = blockIdx.x * blockDim.x + threadIdx.x;
    if (c8 >= V_DIM / 8) return;
    float l = lse[b];
    const u4v* src = (const u4v*)(Lbf + (size_t)b * V_DIM + (size_t)c8 * 8);
    u4v pv = __builtin_nontemporal_load(src);
    f4n q0, q1;
    q0.x = bf2f((ushort)(pv.x & 0xFFFF)) - l;
    q0.y = bf2f((ushort)(pv.x >> 16)) - l;
    q0.z = bf2f((ushort)(pv.y & 0xFFFF)) - l;
    q0.w = bf2f((ushort)(pv.y >> 16)) - l;
    q1.x = bf2f((ushort)(pv.z & 0xFFFF)) - l;
    q1.y = bf2f((ushort)(pv.z >> 16)) - l;
    q1.z = bf2f((ushort)(pv.w & 0xFFFF)) - l;
    q1.w = bf2f((ushort)(pv.w >> 16)) - l;
    float* dst = out + (size_t)b * V_DIM + (size_t)c8 * 8;
    __builtin_nontemporal_store(q0, (f4n*)dst);
    __builtin_nontemporal_store(q1, (f4n*)(dst + 4));
}

extern "C" void kernel_launch(void* const* d_in, const int* in_sizes, int n_in,
                              void* d_out, int out_size, void* d_ws, size_t ws_size,
                              hipStream_t stream) {
    const float* in_input  = (const float*)d_in[0];
    const float* in_hidden = (const float*)d_in[1];
    const float* in_cell   = (const float*)d_in[2];
    const float* We   = (const float*)d_in[3];
    const float* be   = (const float*)d_in[4];
    const float* Wf   = (const float*)d_in[5];
    const float* bfv  = (const float*)d_in[6];
    const float* Wi   = (const float*)d_in[7];
    const float* biv  = (const float*)d_in[8];
    const float* Wc   = (const float*)d_in[9];
    const float* bcv  = (const float*)d_in[10];
    const float* Wo   = (const float*)d_in[11];
    const float* bov  = (const float*)d_in[12];
    const float* Uf   = (const float*)d_in[13];
    const float* bhf  = (const float*)d_in[14];
    const float* Ui   = (const float*)d_in[15];
    const float* bhi  = (const float*)d_in[16];
    const float* Uc   = (const float*)d_in[17];
    const float* bhc  = (const float*)d_in[18];
    const float* Uo   = (const float*)d_in[19];
    const float* bho  = (const float*)d_in[20];
    const float* Wend = (const float*)d_in[21];
    const float* bend = (const float*)d_in[22];

    char* ws = (char*)d_ws;
    const size_t oWendF8 = 0;
    const size_t oHidF8  = oWendF8 + (size_t)V_DIM * H_DIM;
    const size_t oBias2  = oHidF8 + (size_t)B_DIM * H_DIM;
    const size_t oLse    = oBias2 + 4 * H_DIM * 4;
    const size_t oPart   = oLse + B_DIM * 4;
    const size_t oR      = oPart + (size_t)B_DIM * 250 * 8;
    const size_t oAin    = oR;
    const size_t oWeT    = oAin + (size_t)B_DIM * DIN * 2;
    const size_t oA2     = oWeT + (size_t)E_DIM * DIN * 2;
    const size_t oWUT8   = oA2  + (size_t)B_DIM * 4096;

    uint8_t* WendF8 = (uint8_t*)(ws + oWendF8);
    uint8_t* hidF8  = (uint8_t*)(ws + oHidF8);
    float*   bias2  = (float*)(ws + oBias2);
    float*   lse    = (float*)(ws + oLse);
    float2*  part   = (float2*)(ws + oPart);
    ushort*  Lbf    = (ushort*)(ws + oR);
    ushort*  Ain    = (ushort*)(ws + oAin);
    ushort*  WeT    = (ushort*)(ws + oWeT);
    uint8_t* A2     = (uint8_t*)(ws + oA2);
    uint8_t* WUT8   = (uint8_t*)(ws + oWUT8);

    float* out  = (float*)d_out;
    float* outH = out + (size_t)B_DIM * V_DIM;
    float* outC = outH + (size_t)B_DIM * H_DIM;

    const int NCB = V_DIM / 128;   // 250

    dim3 blk256(256), blk64(64);

    // P0: convert input + hidden, transpose all weights, pack biases
    k_cvt<<<dim3((B_DIM * DIN / 4) / 256), blk256, 0, stream>>>(in_input, Ain, B_DIM * DIN / 4);
    k_cvt_hidden<<<dim3((B_DIM * H_DIM / 4) / 256), blk256, 0, stream>>>(in_hidden, A2);

    dim3 tb(32, 8);
    k_transpose_bf16<<<dim3(E_DIM / 32, DIN / 32), tb, 0, stream>>>(We, WeT, E_DIM, DIN, 0, 0);
    k_transpose_gate8<<<dim3(H_DIM / 32, E_DIM / 32, 8), tb, 0, stream>>>(
        Wf, Wi, Wc, Wo, Uf, Ui, Uc, Uo, WUT8);
    k_transpose_fp8<<<dim3(V_DIM / 32, H_DIM / 32), tb, 0, stream>>>(Wend, WendF8, V_DIM, H_DIM);
    k_biaspack<<<dim3(H_DIM / 256), blk256, 0, stream>>>(bfv, bhf, biv, bhi, bcv, bhc, bov, bho, bias2);

    // P1: emb = input @ We + be -> A2 left half (fp8 x32)  [XCD-pinned, grid 32x16]
    k_gemm_bt<<<dim3((B_DIM / 128) * (E_DIM / 128)), blk256, 0, stream>>>(
        Ain, WeT, A2, be, E_DIM, DIN, DIN, DIN, 4096);

    // P2: gates = A2 @ WUT8^T (MX-fp8) + fused LSTM cell -> outH/outC/hidF8  [grid 32x64]
    k_gatemx<<<dim3((B_DIM / 128) * (8192 / 128)), blk256, 0, stream>>>(
        A2, WUT8, bias2, in_cell, outH, outC, hidF8);

    // P3: bf16 logits -> Lbf (coalesced nt), MX-fp8 16x16x128, XCD-pinned
    k_gemm_mx<<<dim3((B_DIM / 128) * (V_DIM / 128)), blk256, 0, stream>>>(
        hidF8, WendF8, Lbf, bend, part, V_DIM, H_DIM, V_DIM, NCB);

    // P4: finish log_softmax
    k_lsefin<<<dim3(B_DIM), blk64, 0, stream>>>(part, lse, NCB);
    k_norm<<<dim3(16, B_DIM), blk256, 0, stream>>>(Lbf, lse, out);
}

// Round 15
// 995.097 us; speedup vs baseline: 1.0909x; 1.0909x over previous
//
#include <hip/hip_runtime.h>
#include <stdint.h>

#define B_DIM 4096
#define DIN   4096
#define E_DIM 2048
#define H_DIM 2048
#define V_DIM 32000

typedef __attribute__((ext_vector_type(8))) short s8v;     // 8 x bf16 (MFMA A/B frag)
typedef __attribute__((ext_vector_type(4))) float f4v;     // MFMA C/D frag
typedef __attribute__((ext_vector_type(4))) int   i4v;
typedef __attribute__((ext_vector_type(8))) int   i8v;     // fp8 MFMA A/B operand (32 B)
typedef __attribute__((ext_vector_type(4))) uint  u4v;     // native 16B int vector (nt ld/st)
typedef __attribute__((ext_vector_type(4))) float f4n;     // native 16B float vector (nt ld/st)

__device__ __forceinline__ ushort f2bf(float f) {
    union { float f; uint32_t u; } v; v.f = f;
    uint32_t u = v.u;
    return (ushort)((u + 0x7FFFu + ((u >> 16) & 1u)) >> 16);
}
__device__ __forceinline__ float bf2f(ushort h) {
    union { uint32_t u; float f; } v; v.u = ((uint32_t)h) << 16;
    return v.f;
}

// float -> OCP e4m3fn, RNE (values expected pre-scaled into normal range)
__device__ __forceinline__ uint8_t f2fp8(float x) {
    union { float f; uint32_t u; } v; v.f = x;
    uint8_t sign = (uint8_t)((v.u >> 24) & 0x80u);
    uint32_t a = v.u & 0x7FFFFFFFu;
    if (a >= 0x43E00000u) return sign | 0x7E;            // >= 448 -> clamp
    uint32_t r = a + 0x0007FFFFu + ((a >> 20) & 1u);     // RNE at bit 20
    int e = (int)(r >> 23) - 127 + 7;
    if (e <= 0) {                                         // subnormal: multiples of 2^-9
        float s = fabsf(x);
        int q = (int)(s * 512.0f + 0.5f);
        if (q > 7) q = 7;
        return sign | (uint8_t)q;
    }
    uint32_t m = (r >> 20) & 7u;
    uint8_t b = (uint8_t)((e << 3) | m);
    if (b == 0x7F) b = 0x7E;                              // avoid NaN encoding
    return sign | b;
}

// ---------------- fp32 -> bf16 plain convert ----------------
__global__ void k_cvt(const float* __restrict__ src, ushort* __restrict__ dst, int n4) {
    int i = blockIdx.x * blockDim.x + threadIdx.x;
    if (i >= n4) return;
    float4 v = *(const float4*)(src + (size_t)i * 4);
    ushort4 o;
    o.x = f2bf(v.x); o.y = f2bf(v.y); o.z = f2bf(v.z); o.w = f2bf(v.w);
    *(ushort4*)(dst + (size_t)i * 4) = o;
}

// hidden [4096][2048] fp32 -> A2 (fp8 x32) right half (row stride 4096, col offset 2048)
__global__ void k_cvt_hidden(const float* __restrict__ src, uint8_t* __restrict__ dst) {
    int i = blockIdx.x * blockDim.x + threadIdx.x;
    int b = i >> 9;
    int c = (i & 511) << 2;
    float4 v = *(const float4*)(src + (size_t)b * H_DIM + c);
    uchar4 o;
    o.x = f2fp8(v.x * 32.0f); o.y = f2fp8(v.y * 32.0f);
    o.z = f2fp8(v.z * 32.0f); o.w = f2fp8(v.w * 32.0f);
    *(uchar4*)(dst + (size_t)b * 4096 + 2048 + c) = o;
}

// ---------------- transpose + convert: src fp32 [K x N] -> dst bf16 [N x K] ----------------
__global__ void k_transpose_bf16(const float* __restrict__ src, ushort* __restrict__ dst,
                                 int srcCols, int dstStride, int dstRowOff, int dstColOff) {
    __shared__ float tile[32][33];
    int tx = threadIdx.x, ty = threadIdx.y;
    int n0 = blockIdx.x * 32, k0 = blockIdx.y * 32;
#pragma unroll
    for (int i = 0; i < 4; i++)
        tile[ty + 8 * i][tx] = src[(size_t)(k0 + ty + 8 * i) * srcCols + n0 + tx];
    __syncthreads();
#pragma unroll
    for (int i = 0; i < 4; i++) {
        int n = ty + 8 * i;
        dst[(size_t)(dstRowOff + n0 + n) * dstStride + dstColOff + k0 + tx] = f2bf(tile[tx][n]);
    }
}

// transpose + convert + scale: src fp32 [K x N] -> dst fp8 [N x K], val*32 (scale 2^-5 in MFMA)
__global__ void k_transpose_fp8(const float* __restrict__ src, uint8_t* __restrict__ dst,
                                int srcCols, int dstStride) {
    __shared__ float tile[32][33];
    int tx = threadIdx.x, ty = threadIdx.y;
    int n0 = blockIdx.x * 32, k0 = blockIdx.y * 32;
#pragma unroll
    for (int i = 0; i < 4; i++)
        tile[ty + 8 * i][tx] = src[(size_t)(k0 + ty + 8 * i) * srcCols + n0 + tx];
    __syncthreads();
#pragma unroll
    for (int i = 0; i < 4; i++) {
        int n = ty + 8 * i;
        dst[(size_t)(n0 + n) * dstStride + k0 + tx] = f2fp8(tile[tx][n] * 32.0f);
    }
}

// all 8 gate-interleaved transposes in one launch -> fp8 (x32), WUT8 [8192][4096]
// 128-col-tile packing: col(g,h) = (h>>5)*128 + ((h>>4)&1)*64 + g*16 + (h&15)
__global__ void k_transpose_gate8(const float* __restrict__ W0, const float* __restrict__ W1,
                                  const float* __restrict__ W2, const float* __restrict__ W3,
                                  const float* __restrict__ U0, const float* __restrict__ U1,
                                  const float* __restrict__ U2, const float* __restrict__ U3,
                                  uint8_t* __restrict__ dst) {
    const float* srcs[8] = {W0, W1, W2, W3, U0, U1, U2, U3};
    int z = blockIdx.z;
    const float* src = srcs[z];
    int g = z & 3;
    int dstColOff = (z >> 2) << 11;   // 0 (W) or 2048 (U)
    __shared__ float tile[32][33];
    int tx = threadIdx.x, ty = threadIdx.y;
    int n0 = blockIdx.x * 32, k0 = blockIdx.y * 32;
#pragma unroll
    for (int i = 0; i < 4; i++)
        tile[ty + 8 * i][tx] = src[(size_t)(k0 + ty + 8 * i) * H_DIM + n0 + tx];
    __syncthreads();
#pragma unroll
    for (int i = 0; i < 4; i++) {
        int h = n0 + ty + 8 * i;
        int drow = ((h >> 5) << 7) + (((h >> 4) & 1) << 6) + (g << 4) + (h & 15);
        dst[(size_t)drow * 4096 + dstColOff + k0 + tx] = f2fp8(tile[tx][ty + 8 * i] * 32.0f);
    }
}

__global__ void k_biaspack(const float* __restrict__ b0, const float* __restrict__ bh0,
                           const float* __restrict__ b1, const float* __restrict__ bh1,
                           const float* __restrict__ b2, const float* __restrict__ bh2,
                           const float* __restrict__ b3, const float* __restrict__ bh3,
                           float* __restrict__ out) {
    int h = blockIdx.x * blockDim.x + threadIdx.x;
    if (h >= H_DIM) return;
    int base = ((h >> 5) << 7) + (((h >> 4) & 1) << 6) + (h & 15);
    out[base]      = b0[h] + bh0[h];   // g=0: f
    out[base + 16] = b1[h] + bh1[h];   // g=1: i
    out[base + 32] = b2[h] + bh2[h];   // g=2: c
    out[base + 48] = b3[h] + bh3[h];   // g=3: o
}

// ---------------- 128x128 2-phase bf16 GEMM (emb only), XCD-pinned ----------------
__global__ __launch_bounds__(256, 2)
void k_gemm_bt(const ushort* __restrict__ A, const ushort* __restrict__ Bt,
               uint8_t* __restrict__ Cf8, const float* __restrict__ bias,
               int N, int K, int lda, int ldb, int ldc) {
    __shared__ __align__(16) ushort ldsA[128 * 64];
    __shared__ __align__(16) ushort ldsB[128 * 64];
    const int t = threadIdx.x;
    const int wid = t >> 6, lane = t & 63;

    int bid = blockIdx.x;
    int mt  = ((bid & 7) << 2) | ((bid >> 3) & 3);
    int nt  = bid >> 5;
    int m0  = mt << 7, n0 = nt << 7;

    f4v acc[4][4];
#pragma unroll
    for (int i = 0; i < 4; i++)
#pragma unroll
        for (int j = 0; j < 4; j++) acc[i][j] = (f4v){0.f, 0.f, 0.f, 0.f};

    const int wr = wid >> 1, wc = wid & 1;

    const int kTiles = K >> 6;
    for (int kt = 0; kt < kTiles; ++kt) {
#pragma unroll
        for (int c = 0; c < 4; ++c) {
            int idx = c * 256 + wid * 64 + lane;
            int row = idx >> 3;
            int kb  = (idx & 7) << 4;
            const ushort* gA = A  + (size_t)(m0 + row) * lda + (kt << 6) + (kb >> 1);
            const ushort* gB = Bt + (size_t)(n0 + row) * ldb + (kt << 6) + (kb >> 1);
            char* lA = (char*)ldsA + (size_t)(c * 256 + wid * 64) * 16;
            char* lB = (char*)ldsB + (size_t)(c * 256 + wid * 64) * 16;
            __builtin_amdgcn_global_load_lds((const __attribute__((address_space(1))) void*)gA,
                                             (__attribute__((address_space(3))) void*)lA, 16, 0, 0);
            __builtin_amdgcn_global_load_lds((const __attribute__((address_space(1))) void*)gB,
                                             (__attribute__((address_space(3))) void*)lB, 16, 0, 0);
        }
        __syncthreads();

#pragma unroll
        for (int ks = 0; ks < 2; ++ks) {
            s8v af[4], bfr[4];
#pragma unroll
            for (int m = 0; m < 4; ++m) {
                int r = wr * 64 + m * 16 + (lane & 15);
                int kb = ks * 64 + ((lane >> 4) << 4);
                af[m] = *(const s8v*)((const char*)ldsA + r * 128 + kb);
            }
#pragma unroll
            for (int n = 0; n < 4; ++n) {
                int r = wc * 64 + n * 16 + (lane & 15);
                int kb = ks * 64 + ((lane >> 4) << 4);
                bfr[n] = *(const s8v*)((const char*)ldsB + r * 128 + kb);
            }
#pragma unroll
            for (int m = 0; m < 4; ++m)
#pragma unroll
                for (int n = 0; n < 4; ++n)
                    acc[m][n] = __builtin_amdgcn_mfma_f32_16x16x32_bf16(af[m], bfr[n], acc[m][n], 0, 0, 0);
        }
        __syncthreads();
    }

#pragma unroll
    for (int n = 0; n < 4; ++n) {
        int cg = n0 + wc * 64 + n * 16 + (lane & 15);
        float bv = bias[cg];
#pragma unroll
        for (int m = 0; m < 4; ++m) {
            int rbase = m0 + wr * 64 + m * 16 + ((lane >> 4) << 2);
#pragma unroll
            for (int r = 0; r < 4; ++r)
                Cf8[(size_t)(rbase + r) * ldc + cg] = f2fp8((acc[m][n][r] + bv) * 32.0f);
        }
    }
}

// ---------------- gate GEMM: MX-fp8 16x16x128, 128x128 tile, BK=128, XCD-pinned ----------------
__global__ __launch_bounds__(256, 3)
void k_gatemx(const uint8_t* __restrict__ A, const uint8_t* __restrict__ Bt,
              const float* __restrict__ bias, const float* __restrict__ cell,
              float* __restrict__ outH, float* __restrict__ outC,
              uint8_t* __restrict__ hidF8) {
    __shared__ __align__(16) uint8_t ldsAB[2][128 * 128];   // 32 KB
    const int t = threadIdx.x;
    const int wid = t >> 6, lane = t & 63;
    const int wrr = wid >> 1, wcc = wid & 1;

    int bid = blockIdx.x;
    int mt  = ((bid & 7) << 2) | ((bid >> 3) & 3);
    int nt  = bid >> 5;                  // 0..63
    int m0  = mt << 7, n0 = nt << 7;
    const int K = 4096;

    int offA[4], offB[4];
#pragma unroll
    for (int c = 0; c < 4; ++c) {
        int idx = c * 256 + t;
        int row = idx >> 3;
        int cb  = ((idx & 7) ^ (row & 7)) << 4;
        offA[c] = (m0 + row) * K + cb;
        offB[c] = (n0 + row) * K + cb;
    }

    f4v acc[4][4];
#pragma unroll
    for (int i = 0; i < 4; ++i)
#pragma unroll
        for (int j = 0; j < 4; ++j) acc[i][j] = (f4v){0.f, 0.f, 0.f, 0.f};

    const int l15 = lane & 15;
    const int sw  = (lane & 7) << 4;
    const int o0  = ((lane >> 4) << 5) ^ sw;
    const int o1  = o0 ^ 16;

    const int kTiles = K >> 7;           // 32
    for (int kt = 0; kt < kTiles; ++kt) {
#pragma unroll
        for (int c = 0; c < 4; ++c) {
            __builtin_amdgcn_global_load_lds(
                (const __attribute__((address_space(1))) void*)(A + offA[c] + (kt << 7)),
                (__attribute__((address_space(3))) void*)&ldsAB[0][(c * 256 + wid * 64) * 16], 16, 0, 0);
            __builtin_amdgcn_global_load_lds(
                (const __attribute__((address_space(1))) void*)(Bt + offB[c] + (kt << 7)),
                (__attribute__((address_space(3))) void*)&ldsAB[1][(c * 256 + wid * 64) * 16], 16, 0, 0);
        }
        __syncthreads();

        i8v af[4], bf[4];
#pragma unroll
        for (int m = 0; m < 4; ++m) {
            int row = wrr * 64 + m * 16 + l15;
            i4v lo = *(const i4v*)&ldsAB[0][row * 128 + o0];
            i4v hi = *(const i4v*)&ldsAB[0][row * 128 + o1];
            af[m] = __builtin_shufflevector(lo, hi, 0, 1, 2, 3, 4, 5, 6, 7);
        }
#pragma unroll
        for (int n = 0; n < 4; ++n) {
            int row = wcc * 64 + n * 16 + l15;
            i4v lo = *(const i4v*)&ldsAB[1][row * 128 + o0];
            i4v hi = *(const i4v*)&ldsAB[1][row * 128 + o1];
            bf[n] = __builtin_shufflevector(lo, hi, 0, 1, 2, 3, 4, 5, 6, 7);
        }
#pragma unroll
        for (int m = 0; m < 4; ++m)
#pragma unroll
            for (int n = 0; n < 4; ++n)
                acc[m][n] = __builtin_amdgcn_mfma_scale_f32_16x16x128_f8f6f4(
                    af[m], bf[n], acc[m][n], 0, 0, 0, 122, 0, 122);
        __syncthreads();
    }

    // ---- fused LSTM epilogue: lane's 4 n-frags = gates f,i,c,o of one h ----
    int h = (n0 >> 2) + wcc * 16 + l15;
    float bv[4];
#pragma unroll
    for (int n = 0; n < 4; ++n) bv[n] = bias[n0 + wcc * 64 + n * 16 + l15];
#pragma unroll
    for (int m = 0; m < 4; ++m) {
#pragma unroll
        for (int r = 0; r < 4; ++r) {
            int b = m0 + wrr * 64 + m * 16 + ((lane >> 4) << 2) + r;
            float pf_ = acc[m][0][r] + bv[0];
            float pi_ = acc[m][1][r] + bv[1];
            float pc_ = acc[m][2][r] + bv[2];
            float po_ = acc[m][3][r] + bv[3];
            float fg = 1.f / (1.f + __expf(-pf_));
            float ig = 1.f / (1.f + __expf(-pi_));
            float gg = tanhf(pc_);
            float og = 1.f / (1.f + __expf(-po_));
            size_t off = (size_t)b * H_DIM + h;
            float nc = fg * cell[off] + ig * gg;
            float nh = og * tanhf(nc);
            outC[off] = nc;
            outH[off] = nh;
            hidF8[off] = f2fp8(nh * 8.0f);   // head A pre-scale 2^3 (scale 124)
        }
    }
}

// ---------------- head GEMM: MX-fp8 16x16x128, 128x128 tile, BK=128, XCD-pinned ----------------
__global__ __launch_bounds__(256, 4)
void k_gemm_mx(const uint8_t* __restrict__ A, const uint8_t* __restrict__ Bt,
               ushort* __restrict__ Lbf, const float* __restrict__ bias,
               float2* __restrict__ partials, int N, int K, int ldc, int ncb) {
    __shared__ __align__(16) uint8_t ldsAB[2][128 * 128];
    __shared__ float2 smStat[256];
    const int t = threadIdx.x;
    const int wid = t >> 6, lane = t & 63;
    const int wrr = wid >> 1, wcc = wid & 1;

    int bid = blockIdx.x;
    int mt  = ((bid & 7) << 2) | ((bid >> 3) & 3);
    int nt  = bid >> 5;                                  // 0..249
    int m0  = mt << 7, n0 = nt << 7;

    int offA[4], offB[4];
#pragma unroll
    for (int c = 0; c < 4; ++c) {
        int idx = c * 256 + t;
        int row = idx >> 3;
        int cb  = ((idx & 7) ^ (row & 7)) << 4;
        offA[c] = (m0 + row) * K + cb;
        offB[c] = (n0 + row) * K + cb;
    }

    f4v acc[4][4];
#pragma unroll
    for (int i = 0; i < 4; ++i)
#pragma unroll
        for (int j = 0; j < 4; ++j) acc[i][j] = (f4v){0.f, 0.f, 0.f, 0.f};

    const int l15 = lane & 15;
    const int sw  = (lane & 7) << 4;
    const int o0  = ((lane >> 4) << 5) ^ sw;
    const int o1  = o0 ^ 16;

    const int kTiles = K >> 7;
    for (int kt = 0; kt < kTiles; ++kt) {
#pragma unroll
        for (int c = 0; c < 4; ++c) {
            __builtin_amdgcn_global_load_lds(
                (const __attribute__((address_space(1))) void*)(A + offA[c] + (kt << 7)),
                (__attribute__((address_space(3))) void*)&ldsAB[0][(c * 256 + wid * 64) * 16], 16, 0, 0);
            __builtin_amdgcn_global_load_lds(
                (const __attribute__((address_space(1))) void*)(Bt + offB[c] + (kt << 7)),
                (__attribute__((address_space(3))) void*)&ldsAB[1][(c * 256 + wid * 64) * 16], 16, 0, 0);
        }
        __syncthreads();

        i8v af[4], bf[4];
#pragma unroll
        for (int m = 0; m < 4; ++m) {
            int row = wrr * 64 + m * 16 + l15;
            i4v lo = *(const i4v*)&ldsAB[0][row * 128 + o0];
            i4v hi = *(const i4v*)&ldsAB[0][row * 128 + o1];
            af[m] = __builtin_shufflevector(lo, hi, 0, 1, 2, 3, 4, 5, 6, 7);
        }
#pragma unroll
        for (int n = 0; n < 4; ++n) {
            int row = wcc * 64 + n * 16 + l15;
            i4v lo = *(const i4v*)&ldsAB[1][row * 128 + o0];
            i4v hi = *(const i4v*)&ldsAB[1][row * 128 + o1];
            bf[n] = __builtin_shufflevector(lo, hi, 0, 1, 2, 3, 4, 5, 6, 7);
        }
#pragma unroll
        for (int m = 0; m < 4; ++m)
#pragma unroll
            for (int n = 0; n < 4; ++n)
                acc[m][n] = __builtin_amdgcn_mfma_scale_f32_16x16x128_f8f6f4(
                    af[m], bf[n], acc[m][n], 0, 0, 0, 124, 0, 122);
        __syncthreads();
    }

    float bv[4];
#pragma unroll
    for (int n = 0; n < 4; ++n) bv[n] = bias[n0 + wcc * 64 + n * 16 + l15];
    ushort* ctile = (ushort*)&ldsAB[0][0];
#pragma unroll
    for (int m = 0; m < 4; ++m) {
#pragma unroll
        for (int r = 0; r < 4; ++r) {
            int rl = wrr * 64 + m * 16 + ((lane >> 4) << 2) + r;
            float v[4];
#pragma unroll
            for (int n = 0; n < 4; ++n) {
                v[n] = acc[m][n][r] + bv[n];
                ctile[rl * 128 + wcc * 64 + n * 16 + l15] = f2bf(v[n]);
            }
            float mx = fmaxf(fmaxf(v[0], v[1]), fmaxf(v[2], v[3]));
            float ss = __expf(v[0] - mx) + __expf(v[1] - mx) +
                       __expf(v[2] - mx) + __expf(v[3] - mx);
#pragma unroll
            for (int off = 1; off < 16; off <<= 1) {
                float mo = __shfl_xor(mx, off);
                float so = __shfl_xor(ss, off);
                float nm = fmaxf(mx, mo);
                ss = ss * __expf(mx - nm) + so * __expf(mo - nm);
                mx = nm;
            }
            if (l15 == 0) smStat[wcc * 128 + rl] = make_float2(mx, ss);
        }
    }
    __syncthreads();
    if (t < 128) {
        float2 a = smStat[t], b = smStat[128 + t];
        float M = fmaxf(a.x, b.x);
        float S = a.y * __expf(a.x - M) + b.y * __expf(b.x - M);
        partials[(size_t)(m0 + t) * ncb + nt] = make_float2(M, S);
    }
#pragma unroll
    for (int i = 0; i < 8; ++i) {
        int idx = i * 256 + t;
        int row = idx >> 4;
        int c16 = idx & 15;
        u4v val = *(const u4v*)&ctile[row * 128 + c16 * 8];
        __builtin_nontemporal_store(val, (u4v*)&Lbf[(size_t)(m0 + row) * ldc + n0 + c16 * 8]);
    }
}

// ---------------- reduce per-block (m,s) partials -> lse[row] ----------------
__global__ void k_lsefin(const float2* __restrict__ part, float* __restrict__ lse, int ncb) {
    int row = blockIdx.x;
    int l = threadIdx.x;   // 64
    float M = -1e30f, S = 0.f;
    for (int i = l; i < ncb; i += 64) {
        float2 p = part[(size_t)row * ncb + i];
        float nm = fmaxf(M, p.x);
        S = S * __expf(M - nm) + p.y * __expf(p.x - nm);
        M = nm;
    }
#pragma unroll
    for (int off = 1; off < 64; off <<= 1) {
        float Mo = __shfl_xor(M, off);
        float So = __shfl_xor(S, off);
        float nm = fmaxf(M, Mo);
        S = S * __expf(M - nm) + So * __expf(Mo - nm);
        M = nm;
    }
    if (l == 0) lse[row] = M + logf(S);
}

// ---------------- normalize: out = bf16logit - lse[row], nontemporal ----------------
__global__ void k_norm(const ushort* __restrict__ Lbf, const float* __restrict__ lse,
                       float* __restrict__ out) {
    int b = blockIdx.y;
    int c8 = blockIdx.x * blockDim.x + threadIdx.x;
    if (c8 >= V_DIM / 8) return;
    float l = lse[b];
    const u4v* src = (const u4v*)(Lbf + (size_t)b * V_DIM + (size_t)c8 * 8);
    u4v pv = __builtin_nontemporal_load(src);
    f4n q0, q1;
    q0.x = bf2f((ushort)(pv.x & 0xFFFF)) - l;
    q0.y = bf2f((ushort)(pv.x >> 16)) - l;
    q0.z = bf2f((ushort)(pv.y & 0xFFFF)) - l;
    q0.w = bf2f((ushort)(pv.y >> 16)) - l;
    q1.x = bf2f((ushort)(pv.z & 0xFFFF)) - l;
    q1.y = bf2f((ushort)(pv.z >> 16)) - l;
    q1.z = bf2f((ushort)(pv.w & 0xFFFF)) - l;
    q1.w = bf2f((ushort)(pv.w >> 16)) - l;
    float* dst = out + (size_t)b * V_DIM + (size_t)c8 * 8;
    __builtin_nontemporal_store(q0, (f4n*)dst);
    __builtin_nontemporal_store(q1, (f4n*)(dst + 4));
}

extern "C" void kernel_launch(void* const* d_in, const int* in_sizes, int n_in,
                              void* d_out, int out_size, void* d_ws, size_t ws_size,
                              hipStream_t stream) {
    const float* in_input  = (const float*)d_in[0];
    const float* in_hidden = (const float*)d_in[1];
    const float* in_cell   = (const float*)d_in[2];
    const float* We   = (const float*)d_in[3];
    const float* be   = (const float*)d_in[4];
    const float* Wf   = (const float*)d_in[5];
    const float* bfv  = (const float*)d_in[6];
    const float* Wi   = (const float*)d_in[7];
    const float* biv  = (const float*)d_in[8];
    const float* Wc   = (const float*)d_in[9];
    const float* bcv  = (const float*)d_in[10];
    const float* Wo   = (const float*)d_in[11];
    const float* bov  = (const float*)d_in[12];
    const float* Uf   = (const float*)d_in[13];
    const float* bhf  = (const float*)d_in[14];
    const float* Ui   = (const float*)d_in[15];
    const float* bhi  = (const float*)d_in[16];
    const float* Uc   = (const float*)d_in[17];
    const float* bhc  = (const float*)d_in[18];
    const float* Uo   = (const float*)d_in[19];
    const float* bho  = (const float*)d_in[20];
    const float* Wend = (const float*)d_in[21];
    const float* bend = (const float*)d_in[22];

    char* ws = (char*)d_ws;
    const size_t oWendF8 = 0;
    const size_t oHidF8  = oWendF8 + (size_t)V_DIM * H_DIM;
    const size_t oBias2  = oHidF8 + (size_t)B_DIM * H_DIM;
    const size_t oLse    = oBias2 + 4 * H_DIM * 4;
    const size_t oPart   = oLse + B_DIM * 4;
    const size_t oR      = oPart + (size_t)B_DIM * 250 * 8;
    const size_t oAin    = oR;
    const size_t oWeT    = oAin + (size_t)B_DIM * DIN * 2;
    const size_t oA2     = oWeT + (size_t)E_DIM * DIN * 2;
    const size_t oWUT8   = oA2  + (size_t)B_DIM * 4096;

    uint8_t* WendF8 = (uint8_t*)(ws + oWendF8);
    uint8_t* hidF8  = (uint8_t*)(ws + oHidF8);
    float*   bias2  = (float*)(ws + oBias2);
    float*   lse    = (float*)(ws + oLse);
    float2*  part   = (float2*)(ws + oPart);
    ushort*  Lbf    = (ushort*)(ws + oR);
    ushort*  Ain    = (ushort*)(ws + oAin);
    ushort*  WeT    = (ushort*)(ws + oWeT);
    uint8_t* A2     = (uint8_t*)(ws + oA2);
    uint8_t* WUT8   = (uint8_t*)(ws + oWUT8);

    float* out  = (float*)d_out;
    float* outH = out + (size_t)B_DIM * V_DIM;
    float* outC = outH + (size_t)B_DIM * H_DIM;

    const int NCB = V_DIM / 128;   // 250

    dim3 blk256(256), blk64(64);

    // P0: convert input + hidden, transpose all weights, pack biases
    k_cvt<<<dim3((B_DIM * DIN / 4) / 256), blk256, 0, stream>>>(in_input, Ain, B_DIM * DIN / 4);
    k_cvt_hidden<<<dim3((B_DIM * H_DIM / 4) / 256), blk256, 0, stream>>>(in_hidden, A2);

    dim3 tb(32, 8);
    k_transpose_bf16<<<dim3(E_DIM / 32, DIN / 32), tb, 0, stream>>>(We, WeT, E_DIM, DIN, 0, 0);
    k_transpose_gate8<<<dim3(H_DIM / 32, E_DIM / 32, 8), tb, 0, stream>>>(
        Wf, Wi, Wc, Wo, Uf, Ui, Uc, Uo, WUT8);
    k_transpose_fp8<<<dim3(V_DIM / 32, H_DIM / 32), tb, 0, stream>>>(Wend, WendF8, V_DIM, H_DIM);
    k_biaspack<<<dim3(H_DIM / 256), blk256, 0, stream>>>(bfv, bhf, biv, bhi, bcv, bhc, bov, bho, bias2);

    // P1: emb = input @ We + be -> A2 left half (fp8 x32)  [XCD-pinned, grid 32x16]
    k_gemm_bt<<<dim3((B_DIM / 128) * (E_DIM / 128)), blk256, 0, stream>>>(
        Ain, WeT, A2, be, E_DIM, DIN, DIN, DIN, 4096);

    // P2: gates = A2 @ WUT8^T (MX-fp8) + fused LSTM cell -> outH/outC/hidF8  [grid 32x64]
    k_gatemx<<<dim3((B_DIM / 128) * (8192 / 128)), blk256, 0, stream>>>(
        A2, WUT8, bias2, in_cell, outH, outC, hidF8);

    // P3: bf16 logits -> Lbf (coalesced nt), MX-fp8 16x16x128, XCD-pinned
    k_gemm_mx<<<dim3((B_DIM / 128) * (V_DIM / 128)), blk256, 0, stream>>>(
        hidF8, WendF8, Lbf, bend, part, V_DIM, H_DIM, V_DIM, NCB);

    // P4: finish log_softmax
    k_lsefin<<<dim3(B_DIM), blk64, 0, stream>>>(part, lse, NCB);
    k_norm<<<dim3(16, B_DIM), blk256, 0, stream>>>(Lbf, lse, out);
}